// Round 13
// baseline (259.234 us; speedup 1.0000x reference)
//
#include <hip/hip_runtime.h>
#include <cmath>

typedef _Float16 half8 __attribute__((ext_vector_type(8)));
typedef float f32x4 __attribute__((ext_vector_type(4)));

#define GLD_LDS16(gptr, lptr)                                                  \
  __builtin_amdgcn_global_load_lds(                                            \
      (const __attribute__((address_space(1))) void*)(gptr),                   \
      (__attribute__((address_space(3))) void*)(lptr), 16, 0, 0)

#define MEMFENCE asm volatile("" ::: "memory")

// ---------------- merged f32 -> f16 conversion (one dispatch) ---------------
__global__ void cvt_all(const float* __restrict__ s0, const float* __restrict__ s1,
                        const float* __restrict__ s2, const float* __restrict__ s3,
                        _Float16* __restrict__ d0, _Float16* __restrict__ d1,
                        _Float16* __restrict__ d2, _Float16* __restrict__ d3,
                        long nb0, long nb1, long nb2) {
  long b = blockIdx.x;
  const float* s;
  _Float16* d;
  if (b < nb0) {
    s = s0; d = d0;
  } else if (b < nb0 + nb1) {
    s = s1; d = d1; b -= nb0;
  } else if (b < nb0 + nb1 + nb2) {
    s = s2; d = d2; b -= nb0 + nb1;
  } else {
    s = s3; d = d3; b -= nb0 + nb1 + nb2;
  }
  long i = b * 2048 + (long)threadIdx.x * 8;
  const float4* p = (const float4*)(s + i);
  float4 a = p[0];
  float4 c = p[1];
  half8 h = {(_Float16)a.x, (_Float16)a.y, (_Float16)a.z, (_Float16)a.w,
             (_Float16)c.x, (_Float16)c.y, (_Float16)c.z, (_Float16)c.w};
  *(half8*)(d + i) = h;
}

// ---------------- merge + bias + 0.5*tanh (split-K reduction) ---------------
// out[i] = 0.5*tanh(p0[i] + p1[i] + bias[i % N]);  N power of 2.
// Grid must cover B*H/(256*8) blocks exactly (no grid-stride).
__global__ void merge_act(const _Float16* __restrict__ p0,
                          const _Float16* __restrict__ p1,
                          const float* __restrict__ bias,
                          _Float16* __restrict__ out, int N) {
  long i = ((long)blockIdx.x * blockDim.x + threadIdx.x) * 8;
  half8 a = *(const half8*)(p0 + i);
  half8 b = *(const half8*)(p1 + i);
  const float* bp = bias + ((int)i & (N - 1));
  half8 r;
#pragma unroll
  for (int j = 0; j < 8; j++) {
    float v = (float)a[j] + (float)b[j] + bp[j];
    r[j] = (_Float16)(0.5f * tanhf(v));
  }
  *(half8*)(out + i) = r;
}

// ---------------- r7 GEMM (proven): C[m,n] = sum_k A[m,k]*B[n,k] ------------
// EPI: 0 = acc+bias -> f16 ; 1 = 0.5*tanh(acc+bias) -> f16 ; 2 = acc+bias -> f32
// BM=256, BK=64, 8 waves (4M x 2N), triple-buffer, 1 barrier/K-tile, counted
// vmcnt. Used for embed (EPI0,NW4), head (EPI2,NW2), and the fallback path.
template <int EPI, int NW>
__global__ __launch_bounds__(512, 2) void gemm1b(
    const _Float16* __restrict__ A, const _Float16* __restrict__ Bm,
    const float* __restrict__ bias, void* __restrict__ Cout, int N, int K) {
  constexpr int BN = NW * 32;
  constexpr int BLOADS = BN / 64;
  __shared__ _Float16 As[3][256 * 64];
  __shared__ _Float16 Bs[3][BN * 64];

  const int tid = threadIdx.x;
  const int lane = tid & 63;
  const int wave = tid >> 6;

  const int bid = blockIdx.x;
  const int xcd = bid & 7;
  const int idx = bid >> 3;
  const int brow = ((xcd >> 1) * 4 + (idx & 3)) * 256;
  const int bcol = ((xcd & 1) * 8 + (idx >> 2)) * BN;

  const int wr = (wave >> 1) * 64;
  const int wc = (wave & 1) * (BN / 2);

  const int sr = tid >> 3;
  const int sc = ((tid & 7) ^ (sr & 7)) * 8;
  const _Float16* Ag = A + (size_t)(brow + sr) * K + sc;
  const _Float16* Bg = Bm + (size_t)(bcol + sr) * K + sc;
  const int ldst = tid * 8;

  const int frow = lane & 15;
  const int hi = lane >> 4;
  const int xr = lane & 7;

  int aoff[4], boff[NW];
#pragma unroll
  for (int m = 0; m < 4; m++) aoff[m] = (wr + m * 16 + frow) * 64;
#pragma unroll
  for (int n = 0; n < NW; n++) boff[n] = (wc + n * 16 + frow) * 64;
  const int ch0 = (hi ^ xr) * 8;
  const int ch1 = ((4 + hi) ^ xr) * 8;

  f32x4 acc[4][NW];
#pragma unroll
  for (int m = 0; m < 4; m++)
#pragma unroll
    for (int n = 0; n < NW; n++) acc[m][n] = f32x4{0.f, 0.f, 0.f, 0.f};

  _Float16* sa0 = As[0]; _Float16* sa1 = As[1]; _Float16* sa2 = As[2];
  _Float16* sb0 = Bs[0]; _Float16* sb1 = Bs[1]; _Float16* sb2 = Bs[2];

  auto stage = [&](_Float16* sa, _Float16* sb, int t) {
    const _Float16* ag = Ag + t * 64;
#pragma unroll
    for (int i = 0; i < 4; i++)
      GLD_LDS16(ag + (size_t)i * 64 * K, sa + i * 4096 + ldst);
#pragma unroll
    for (int i = 0; i < BLOADS; i++)
      GLD_LDS16(Bg + t * 64 + (size_t)i * 64 * K, sb + i * 4096 + ldst);
  };

  const int nt = K >> 6;

  stage(sa0, sb0, 0);
  stage(sa1, sb1, 1);
  if constexpr (NW == 4)
    asm volatile("s_waitcnt vmcnt(6)" ::: "memory");
  else
    asm volatile("s_waitcnt vmcnt(5)" ::: "memory");
  __builtin_amdgcn_s_barrier();
  MEMFENCE;

  for (int t = 0; t < nt; ++t) {
    half8 a0[4], a1[4], b0[NW], b1[NW];
#pragma unroll
    for (int m = 0; m < 4; m++) a0[m] = *(const half8*)(sa0 + aoff[m] + ch0);
#pragma unroll
    for (int n = 0; n < NW; n++) b0[n] = *(const half8*)(sb0 + boff[n] + ch0);
#pragma unroll
    for (int m = 0; m < 4; m++) a1[m] = *(const half8*)(sa0 + aoff[m] + ch1);
#pragma unroll
    for (int n = 0; n < NW; n++) b1[n] = *(const half8*)(sb0 + boff[n] + ch1);

    if (t + 2 < nt) {
      stage(sa2, sb2, t + 2);
      if constexpr (NW == 4)
        asm volatile("s_waitcnt vmcnt(6)" ::: "memory");
      else
        asm volatile("s_waitcnt vmcnt(5)" ::: "memory");
    } else {
      asm volatile("s_waitcnt vmcnt(0)" ::: "memory");
    }
    asm volatile("s_waitcnt lgkmcnt(0)" ::: "memory");
    __builtin_amdgcn_s_barrier();
    MEMFENCE;

    __builtin_amdgcn_s_setprio(1);
#pragma unroll
    for (int m = 0; m < 4; m++)
#pragma unroll
      for (int n = 0; n < NW; n++)
        acc[m][n] =
            __builtin_amdgcn_mfma_f32_16x16x32_f16(a0[m], b0[n], acc[m][n], 0, 0, 0);
#pragma unroll
    for (int m = 0; m < 4; m++)
#pragma unroll
      for (int n = 0; n < NW; n++)
        acc[m][n] =
            __builtin_amdgcn_mfma_f32_16x16x32_f16(a1[m], b1[n], acc[m][n], 0, 0, 0);
    __builtin_amdgcn_s_setprio(0);
    MEMFENCE;

    _Float16* ta = sa0; sa0 = sa1; sa1 = sa2; sa2 = ta;
    _Float16* tb = sb0; sb0 = sb1; sb1 = sb2; sb2 = tb;
  }

  const int r0 = hi * 4;
  const int c0 = frow;
#pragma unroll
  for (int n = 0; n < NW; n++) {
    const int col = bcol + wc + n * 16 + c0;
    const float bv = bias[col];
#pragma unroll
    for (int m = 0; m < 4; m++) {
#pragma unroll
      for (int r = 0; r < 4; r++) {
        const int row = brow + wr + m * 16 + r0 + r;
        float v = acc[m][n][r] + bv;
        if (EPI == 1) v = 0.5f * tanhf(v);
        if (EPI == 2)
          ((float*)Cout)[(size_t)row * N + col] = v;
        else
          ((_Float16*)Cout)[(size_t)row * N + col] = (_Float16)v;
      }
    }
  }
}

// ---------------- split-K GEMM half: raw f16 partial -------------------------
// BM=256, BN=128, BK=32, 8 waves (4M x 2N), TRIPLE-buffer LDS = 72 KB ->
// 2 blocks/CU (grid 512 = 2 splits x 256 tiles): two desynchronized blocks
// per CU cover each other's stalls (the m97/m114 occupancy mechanism) while
// keeping the r7 counted-vmcnt 1-barrier anatomy. launch_bounds(512,4) caps
// VGPR at 128 so 16 waves/CU fit. Swizzle: chunk ^ (row&3) (4 chunks/row).
// Each half sums K/2 and writes a raw f16 partial (f32 accum; no bias).
__global__ __launch_bounds__(512, 4) void gemmsk(
    const _Float16* __restrict__ A, const _Float16* __restrict__ Bm,
    _Float16* __restrict__ P0, _Float16* __restrict__ P1, int N, int K) {
  __shared__ _Float16 As[3][256 * 32];
  __shared__ _Float16 Bs[3][128 * 32];

  const int tid = threadIdx.x;
  const int lane = tid & 63;
  const int wave = tid >> 6;

  const int bid = blockIdx.x;
  const int s = bid & 1;        // K-split half
  const int tb = bid >> 1;      // tile 0..255
  const int xcd = tb & 7;
  const int idx = tb >> 3;
  const int brow = ((xcd >> 1) * 4 + (idx & 3)) * 256;
  const int bcol = ((xcd & 1) * 8 + (idx >> 2)) * 128;
  const int kbase = s * (K >> 1);

  const int wr = (wave >> 1) * 64;
  const int wc = (wave & 1) * 64;

  // staging: thread -> row sr (0..127), chunk scc (0..3), 16B each.
  const int sr = tid >> 2;
  const int scc = tid & 3;
  const int sc = (scc ^ (sr & 3)) * 8;  // T2 pre-swizzled source col
  const _Float16* Ag = A + (size_t)(brow + sr) * K + sc + kbase;
  const _Float16* Bg = Bm + (size_t)(bcol + sr) * K + sc + kbase;
  const int ldst = tid * 8;

  const int frow = lane & 15;
  const int hi = lane >> 4;
  const int xr3 = lane & 3;  // read-side XOR (4 chunks/row)

  int aoff[4], boff[4];
#pragma unroll
  for (int m = 0; m < 4; m++) aoff[m] = (wr + m * 16 + frow) * 32;
#pragma unroll
  for (int n = 0; n < 4; n++) boff[n] = (wc + n * 16 + frow) * 32;
  const int ch = (hi ^ xr3) * 8;

  f32x4 acc[4][4];
#pragma unroll
  for (int m = 0; m < 4; m++)
#pragma unroll
    for (int n = 0; n < 4; n++) acc[m][n] = f32x4{0.f, 0.f, 0.f, 0.f};

  _Float16* sa0 = As[0]; _Float16* sa1 = As[1]; _Float16* sa2 = As[2];
  _Float16* sb0 = Bs[0]; _Float16* sb1 = Bs[1]; _Float16* sb2 = Bs[2];

  auto stage = [&](_Float16* sa, _Float16* sb, int t) {
    const _Float16* ag = Ag + t * 32;
    GLD_LDS16(ag, sa + ldst);
    GLD_LDS16(ag + (size_t)128 * K, sa + 4096 + ldst);
    GLD_LDS16(Bg + t * 32, sb + ldst);
  };

  const int nt = K >> 6;  // (K/2)/32 K-tiles per half

  stage(sa0, sb0, 0);
  stage(sa1, sb1, 1);
  asm volatile("s_waitcnt vmcnt(3)" ::: "memory");
  __builtin_amdgcn_s_barrier();
  MEMFENCE;

  for (int t = 0; t < nt; ++t) {
    half8 a[4], b[4];
#pragma unroll
    for (int m = 0; m < 4; m++) a[m] = *(const half8*)(sa0 + aoff[m] + ch);
#pragma unroll
    for (int n = 0; n < 4; n++) b[n] = *(const half8*)(sb0 + boff[n] + ch);

    if (t + 2 < nt) {
      stage(sa2, sb2, t + 2);
      asm volatile("s_waitcnt vmcnt(3)" ::: "memory");
    } else {
      asm volatile("s_waitcnt vmcnt(0)" ::: "memory");
    }
    asm volatile("s_waitcnt lgkmcnt(0)" ::: "memory");
    __builtin_amdgcn_s_barrier();
    MEMFENCE;

    __builtin_amdgcn_s_setprio(1);
#pragma unroll
    for (int m = 0; m < 4; m++)
#pragma unroll
      for (int n = 0; n < 4; n++)
        acc[m][n] =
            __builtin_amdgcn_mfma_f32_16x16x32_f16(a[m], b[n], acc[m][n], 0, 0, 0);
    __builtin_amdgcn_s_setprio(0);
    MEMFENCE;

    _Float16* ta = sa0; sa0 = sa1; sa1 = sa2; sa2 = ta;
    _Float16* tb = sb0; sb0 = sb1; sb1 = sb2; sb2 = tb;
  }

  _Float16* P = s ? P1 : P0;
  const int r0 = hi * 4;
  const int c0 = frow;
#pragma unroll
  for (int n = 0; n < 4; n++) {
    const int col = bcol + wc + n * 16 + c0;
#pragma unroll
    for (int m = 0; m < 4; m++) {
#pragma unroll
      for (int r = 0; r < 4; r++) {
        const int row = brow + wr + m * 16 + r0 + r;
        P[(size_t)row * N + col] = (_Float16)acc[m][n][r];
      }
    }
  }
}

// ---------------------------------------------------------------------------
extern "C" void kernel_launch(void* const* d_in, const int* in_sizes, int n_in,
                              void* d_out, int out_size, void* d_ws,
                              size_t ws_size, hipStream_t stream) {
  (void)in_sizes;
  (void)n_in;

  const float* x = (const float*)d_in[0];        // [4096,1024]
  const float* W_embed = (const float*)d_in[1];  // [2048,1024]
  const float* b_embed = (const float*)d_in[2];  // [2048]
  const float* W_layers = (const float*)d_in[3]; // [3,2048,2048]
  const float* b_layers = (const float*)d_in[4]; // [3,2048]
  const float* W_head = (const float*)d_in[5];   // [1024,2048]
  const float* b_head = (const float*)d_in[6];   // [1024]

  const int B = 4096, I = 1024, H = 2048, O = 1024;

  char* w = (char*)d_ws;
  size_t used = 0;
  auto carve = [&](size_t bytes) {
    char* p = w + used;
    used += (bytes + 255) & ~(size_t)255;
    return p;
  };
  _Float16* xh = (_Float16*)carve((size_t)B * I * 2);
  _Float16* Weh = (_Float16*)carve((size_t)H * I * 2);
  _Float16* Wlh = (_Float16*)carve((size_t)3 * H * H * 2);
  _Float16* Whh = (_Float16*)carve((size_t)O * H * 2);
  _Float16* bufE = (_Float16*)carve((size_t)B * H * 2);
  _Float16* bufA = (_Float16*)carve((size_t)B * H * 2);
  const size_t p0_bytes = (size_t)B * H * 2;

  const long n0 = (long)B * I, n1 = (long)H * I, n2 = (long)3 * H * H,
             n3 = (long)O * H;
  const long nb0 = n0 / 2048, nb1 = n1 / 2048, nb2 = n2 / 2048,
             nb3 = n3 / 2048;
  cvt_all<<<(int)(nb0 + nb1 + nb2 + nb3), 256, 0, stream>>>(
      x, W_embed, W_layers, W_head, xh, Weh, Wlh, Whh, nb0, nb1, nb2);

  dim3 blk(512);
  // x_emb = x @ W_embed^T + b_embed            [B,H], f16
  gemm1b<0, 4><<<256, blk, 0, stream>>>(xh, Weh, b_embed, bufE, H, I);

  const bool splitk = (ws_size >= used + p0_bytes) &&
                      ((size_t)out_size * 4 >= (size_t)B * H * 2);
  if (splitk) {
    _Float16* P0 = (_Float16*)carve(p0_bytes);
    _Float16* P1 = (_Float16*)d_out;  // d_out doubles as partial #1 (exact fit)
    const int mb = (int)((long)B * H / (256 * 8));  // 4096 merge blocks

    // h0 = 0.5*tanh(x_emb @ W0^T + b0)
    gemmsk<<<512, blk, 0, stream>>>(bufE, Wlh, P0, P1, H, H);
    merge_act<<<mb, 256, 0, stream>>>(P0, P1, b_layers, bufA, H);
    // h1
    gemmsk<<<512, blk, 0, stream>>>(bufA, Wlh + (size_t)H * H, P0, P1, H, H);
    merge_act<<<mb, 256, 0, stream>>>(P0, P1, b_layers + H, bufE, H);
    // h2
    gemmsk<<<512, blk, 0, stream>>>(bufE, Wlh + (size_t)2 * H * H, P0, P1, H, H);
    merge_act<<<mb, 256, 0, stream>>>(P0, P1, b_layers + 2 * H, bufA, H);
  } else {
    // fallback: proven r7 path
    gemm1b<1, 4><<<256, blk, 0, stream>>>(bufE, Wlh, b_layers, bufA, H, H);
    gemm1b<1, 4><<<256, blk, 0, stream>>>(bufA, Wlh + (size_t)H * H,
                                          b_layers + H, bufE, H, H);
    gemm1b<1, 4><<<256, blk, 0, stream>>>(bufE, Wlh + (size_t)2 * H * H,
                                          b_layers + 2 * H, bufA, H, H);
    // h2 ends in bufA either way for the head
  }

  // out = h2 @ W_head^T + b_head               [B,O], f32  (BN=64)
  gemm1b<2, 2><<<256, blk, 0, stream>>>(bufA, Whh, b_head, d_out, O, H);
}

// Round 15
// 185.342 us; speedup vs baseline: 1.3987x; 1.3987x over previous
//
#include <hip/hip_runtime.h>
#include <cmath>

typedef _Float16 half8 __attribute__((ext_vector_type(8)));
typedef float f32x4 __attribute__((ext_vector_type(4)));

#define GLD_LDS16(gptr, lptr)                                                  \
  __builtin_amdgcn_global_load_lds(                                            \
      (const __attribute__((address_space(1))) void*)(gptr),                   \
      (__attribute__((address_space(3))) void*)(lptr), 16, 0, 0)

#define MEMFENCE asm volatile("" ::: "memory")

// ---------------- merged f32 -> f16 conversion (one dispatch) ---------------
__global__ void cvt_all(const float* __restrict__ s0, const float* __restrict__ s1,
                        const float* __restrict__ s2, const float* __restrict__ s3,
                        _Float16* __restrict__ d0, _Float16* __restrict__ d1,
                        _Float16* __restrict__ d2, _Float16* __restrict__ d3,
                        long nb0, long nb1, long nb2) {
  long b = blockIdx.x;
  const float* s;
  _Float16* d;
  if (b < nb0) {
    s = s0; d = d0;
  } else if (b < nb0 + nb1) {
    s = s1; d = d1; b -= nb0;
  } else if (b < nb0 + nb1 + nb2) {
    s = s2; d = d2; b -= nb0 + nb1;
  } else {
    s = s3; d = d3; b -= nb0 + nb1 + nb2;
  }
  long i = b * 2048 + (long)threadIdx.x * 8;
  const float4* p = (const float4*)(s + i);
  float4 a = p[0];
  float4 c = p[1];
  half8 h = {(_Float16)a.x, (_Float16)a.y, (_Float16)a.z, (_Float16)a.w,
             (_Float16)c.x, (_Float16)c.y, (_Float16)c.z, (_Float16)c.w};
  *(half8*)(d + i) = h;
}

// ---------------- wave-specialized GEMM: C[m,n] = sum_k A[m,k]*B[n,k] -------
// EPI: 0 = acc+bias -> f16 ; 1 = 0.5*tanh(acc+bias) -> f16 ; 2 = acc+bias -> f32
// NW:  B-fragments per consumer wave. BN = NW*32 (4 -> BN=128, 2 -> BN=64).
// 768 threads = 8 CONSUMER waves (4M x 2N, 64 x BN/2 each — identical math to
// the proven r7 kernel) + 4 PRODUCER waves (staging only).
// Mechanism: vmcnt is per-wave. Consumers never touch global memory in the
// K-loop -> no vmcnt in their timeline; producers absorb all HBM/L2 latency.
//   consumer/K-tile: 16 ds_read -> setprio(1) 32 MFMA setprio(0)
//                    -> lgkmcnt(0) [WAR] -> s_barrier
//   producer/K-tile: IPW=8+BN/32 gld_lds (tile t+2; each wave-issue moves
//                    64 lanes x 16B = 1KB = 8 rows x 64 cols) -> vmcnt(IPW)
//                    [tile t+1 landed; t+2 stays in flight] -> s_barrier
// COVERAGE (r14 bugfix): 4 waves x IPW KB = full 48KB tile (NW=4); each wave
// owns A rows [pw*64, pw*64+64) (8 issues) + B rows [pw*BN/4, ...) (BN/32).
// Triple-buffer slots: read t%3, stage (t+2)%3. RAW: producer vmcnt one
// barrier before consumption. WAR: consumer lgkmcnt(0) before the barrier
// that licenses re-staging of its slot (reads of that slot ended 1 iter ago).
// T2 XOR swizzle via pre-swizzled producer SOURCE address: position (l&7) of
// row r holds source chunk (l&7)^(r&7) — bit-identical to the r7 layout;
// consumer read offsets unchanged.
// Grid: 256 blocks = 16x16 tiles; 2-D XCD rects (4 rows x 8 cols of tiles).
template <int EPI, int NW>
__global__ __launch_bounds__(768, 3) void gemmws(
    const _Float16* __restrict__ A, const _Float16* __restrict__ Bm,
    const float* __restrict__ bias, void* __restrict__ Cout, int N, int K) {
  constexpr int BN = NW * 32;
  __shared__ _Float16 As[3][256 * 64];
  __shared__ _Float16 Bs[3][BN * 64];

  const int tid = threadIdx.x;
  const int lane = tid & 63;
  const int wave = tid >> 6;

  // 2-D XCD rects on the 16x16 tile grid (256 blocks): each XCD owns 4x8.
  const int bid = blockIdx.x;
  const int xcd = bid & 7;
  const int idx = bid >> 3;
  const int brow = ((xcd >> 1) * 4 + (idx & 3)) * 256;
  const int bcol = ((xcd & 1) * 8 + (idx >> 2)) * BN;

  const int nt = K >> 6;

  _Float16* sa0 = As[0]; _Float16* sa1 = As[1]; _Float16* sa2 = As[2];
  _Float16* sb0 = Bs[0]; _Float16* sb1 = Bs[1]; _Float16* sb2 = Bs[2];

  if (wave < 8) {
    // =========================== CONSUMER ===========================
    const int wr = (wave >> 1) * 64;        // 4 M-waves, 64 rows each
    const int wc = (wave & 1) * (BN / 2);   // 2 N-waves

    const int frow = lane & 15;
    const int hi = lane >> 4;
    const int xr = lane & 7;  // read-side XOR (matches producer swizzle)

    int aoff[4], boff[NW];
#pragma unroll
    for (int m = 0; m < 4; m++) aoff[m] = (wr + m * 16 + frow) * 64;
#pragma unroll
    for (int n = 0; n < NW; n++) boff[n] = (wc + n * 16 + frow) * 64;
    const int ch0 = (hi ^ xr) * 8;
    const int ch1 = ((4 + hi) ^ xr) * 8;

    f32x4 acc[4][NW];
#pragma unroll
    for (int m = 0; m < 4; m++)
#pragma unroll
      for (int n = 0; n < NW; n++) acc[m][n] = f32x4{0.f, 0.f, 0.f, 0.f};

    __builtin_amdgcn_s_barrier();  // prologue: tile 0 published by producers
    MEMFENCE;

    for (int t = 0; t < nt; ++t) {
      half8 a0[4], a1[4], b0[NW], b1[NW];
#pragma unroll
      for (int m = 0; m < 4; m++) a0[m] = *(const half8*)(sa0 + aoff[m] + ch0);
#pragma unroll
      for (int n = 0; n < NW; n++) b0[n] = *(const half8*)(sb0 + boff[n] + ch0);
#pragma unroll
      for (int m = 0; m < 4; m++) a1[m] = *(const half8*)(sa0 + aoff[m] + ch1);
#pragma unroll
      for (int n = 0; n < NW; n++) b1[n] = *(const half8*)(sb0 + boff[n] + ch1);

      __builtin_amdgcn_s_setprio(1);
#pragma unroll
      for (int m = 0; m < 4; m++)
#pragma unroll
        for (int n = 0; n < NW; n++)
          acc[m][n] = __builtin_amdgcn_mfma_f32_16x16x32_f16(a0[m], b0[n],
                                                             acc[m][n], 0, 0, 0);
#pragma unroll
      for (int m = 0; m < 4; m++)
#pragma unroll
        for (int n = 0; n < NW; n++)
          acc[m][n] = __builtin_amdgcn_mfma_f32_16x16x32_f16(a1[m], b1[n],
                                                             acc[m][n], 0, 0, 0);
      __builtin_amdgcn_s_setprio(0);

      asm volatile("s_waitcnt lgkmcnt(0)" ::: "memory");  // reads drained (WAR)
      __builtin_amdgcn_s_barrier();
      MEMFENCE;

      _Float16* ta = sa0; sa0 = sa1; sa1 = sa2; sa2 = ta;
      _Float16* tb = sb0; sb0 = sb1; sb1 = sb2; sb2 = tb;
    }

    // epilogue: C/D layout col = lane&15, row = (lane>>4)*4 + reg
    const int r0 = hi * 4;
    const int c0 = frow;
#pragma unroll
    for (int n = 0; n < NW; n++) {
      const int col = bcol + wc + n * 16 + c0;
      const float bv = bias[col];
#pragma unroll
      for (int m = 0; m < 4; m++) {
#pragma unroll
        for (int r = 0; r < 4; r++) {
          const int row = brow + wr + m * 16 + r0 + r;
          float v = acc[m][n][r] + bv;
          if (EPI == 1) v = 0.5f * tanhf(v);
          if (EPI == 2)
            ((float*)Cout)[(size_t)row * N + col] = v;
          else
            ((_Float16*)Cout)[(size_t)row * N + col] = (_Float16)v;
        }
      }
    }
  } else {
    // =========================== PRODUCER ===========================
    const int pw = wave - 8;            // 0..3
    const int prr = lane >> 3;          // 0..7  row within an 8-row issue
    const int pcol = ((lane & 7) ^ prr) * 8;  // T2 pre-swizzled source col
    const _Float16* Ab = A + (size_t)(brow + prr) * K + pcol;
    const _Float16* Bb = Bm + (size_t)(bcol + prr) * K + pcol;
    const int pdst = lane * 8;          // linear dest: (l>>3)*64 + (l&7)*8
    constexpr int BI = BN / 32;         // B issues per wave (4 or 2)
    constexpr int IPW = 8 + BI;         // issues per wave per tile (12 or 10)

    auto stageTo = [&](_Float16* pa, _Float16* pb, int t) {
#pragma unroll
      for (int i = 0; i < 8; i++) {
        const int r = pw * 64 + i * 8;  // A rows [pw*64, pw*64+64)
        GLD_LDS16(Ab + (size_t)r * K + t * 64, pa + r * 64 + pdst);
      }
#pragma unroll
      for (int i = 0; i < BI; i++) {
        const int r = pw * (BN / 4) + i * 8;  // B rows [pw*BN/4, ...)
        GLD_LDS16(Bb + (size_t)r * K + t * 64, pb + r * 64 + pdst);
      }
    };

    // prologue: tiles 0,1; wait tile 0 (tile 1 in flight); publish
    stageTo(sa0, sb0, 0);
    stageTo(sa1, sb1, 1);
    asm volatile("s_waitcnt vmcnt(%0)" ::"i"(IPW) : "memory");
    __builtin_amdgcn_s_barrier();
    MEMFENCE;

    for (int t = 0; t < nt; ++t) {
      if (t + 2 < nt) {
        stageTo(sa2, sb2, t + 2);
        asm volatile("s_waitcnt vmcnt(%0)" ::"i"(IPW) : "memory");  // t+1 in
      } else {
        asm volatile("s_waitcnt vmcnt(0)" ::: "memory");  // tail drain
      }
      __builtin_amdgcn_s_barrier();
      MEMFENCE;

      _Float16* ta = sa0; sa0 = sa1; sa1 = sa2; sa2 = ta;
      _Float16* tb = sb0; sb0 = sb1; sb1 = sb2; sb2 = tb;
    }
  }
}

// ---------------------------------------------------------------------------
extern "C" void kernel_launch(void* const* d_in, const int* in_sizes, int n_in,
                              void* d_out, int out_size, void* d_ws,
                              size_t ws_size, hipStream_t stream) {
  (void)in_sizes;
  (void)n_in;
  (void)out_size;
  (void)ws_size;

  const float* x = (const float*)d_in[0];        // [4096,1024]
  const float* W_embed = (const float*)d_in[1];  // [2048,1024]
  const float* b_embed = (const float*)d_in[2];  // [2048]
  const float* W_layers = (const float*)d_in[3]; // [3,2048,2048]
  const float* b_layers = (const float*)d_in[4]; // [3,2048]
  const float* W_head = (const float*)d_in[5];   // [1024,2048]
  const float* b_head = (const float*)d_in[6];   // [1024]

  const int B = 4096, I = 1024, H = 2048, O = 1024;

  char* w = (char*)d_ws;
  auto carve = [&](size_t bytes) {
    char* p = w;
    w += (bytes + 255) & ~(size_t)255;
    return p;
  };
  _Float16* xh = (_Float16*)carve((size_t)B * I * 2);
  _Float16* Weh = (_Float16*)carve((size_t)H * I * 2);
  _Float16* Wlh = (_Float16*)carve((size_t)3 * H * H * 2);
  _Float16* Whh = (_Float16*)carve((size_t)O * H * 2);
  _Float16* bufE = (_Float16*)carve((size_t)B * H * 2);
  _Float16* bufA = (_Float16*)carve((size_t)B * H * 2);

  const long n0 = (long)B * I, n1 = (long)H * I, n2 = (long)3 * H * H,
             n3 = (long)O * H;
  const long nb0 = n0 / 2048, nb1 = n1 / 2048, nb2 = n2 / 2048,
             nb3 = n3 / 2048;
  cvt_all<<<(int)(nb0 + nb1 + nb2 + nb3), 256, 0, stream>>>(
      x, W_embed, W_layers, W_head, xh, Weh, Wlh, Whh, nb0, nb1, nb2);

  dim3 blk(768);
  // all grids: 16x16 tiles = 256 blocks = 1 block/CU (12 waves each)
  // x_emb = x @ W_embed^T + b_embed            [B,H], f16
  gemmws<0, 4><<<256, blk, 0, stream>>>(xh, Weh, b_embed, bufE, H, I);
  // h0 = 0.5*tanh(x_emb @ W0^T + b0)           [B,H], f16
  gemmws<1, 4><<<256, blk, 0, stream>>>(bufE, Wlh, b_layers, bufA, H, H);
  // h1 = 0.5*tanh(h0 @ W1^T + b1)              [B,H], f16
  gemmws<1, 4><<<256, blk, 0, stream>>>(bufA, Wlh + (size_t)H * H,
                                        b_layers + H, bufE, H, H);
  // h2 = 0.5*tanh(h1 @ W2^T + b2)              [B,H], f16
  gemmws<1, 4><<<256, blk, 0, stream>>>(bufE, Wlh + (size_t)2 * H * H,
                                        b_layers + 2 * H, bufA, H, H);
  // out = h2 @ W_head^T + b_head               [B,O], f32  (BN=64)
  gemmws<2, 2><<<256, blk, 0, stream>>>(bufA, Whh, b_head, d_out, O, H);
}